// Round 1
// baseline (786.110 us; speedup 1.0000x reference)
//
#include <hip/hip_runtime.h>

// SLAYER SRM-alpha constants (fp32-rounded from the reference doubles)
#define D_SR   0.90483741803595952f   // exp(-1/10)
#define D_REF  0.36787944117144233f   // exp(-1)
#define PSPSC  0.27182818284590454f   // e/10
#define THETA  10.0f
#define REFSC  20.0f                  // scaleRef * theta
#define POOLSC 2.75f                  // 1.1*theta/4

// One SRM step: two cascaded IIR stages (alpha PSP), threshold, exp refractory.
__device__ __forceinline__ float snstep(float x, float& g1, float& g2, float& r) {
  g1 = D_SR * g1 + x;
  g2 = D_SR * g2 + g1;
  const float u = PSPSC * (g2 - g1) + r - THETA;
  const float s = (u >= 0.0f) ? 1.0f : 0.0f;
  r = D_REF * (r - REFSC * s);
  return s;
}

// ---------------------------------------------------------------------------
// Per-timestep 2D conv (kernel depth 1 in T). Layout NCHWT, T=256 contiguous.
// Thread = (b, h, w, t4). Lane == t4 -> coalesced float4 loads/stores along T.
// Each thread accumulates CoG output channels in registers; weights in LDS.
// __any()-zero skip: post-layer-1 tensors are all-zero (u << theta), so the
// FMA block is skipped wave-uniformly and conv2..4 become load-bound.
// ---------------------------------------------------------------------------
template<int Ci, int K, int P, int Co, int CoG, int CiCh, int H, int W>
__global__ __launch_bounds__(256)
void conv_kernel(const float* __restrict__ in, const float* __restrict__ wt,
                 float* __restrict__ out) {
  __shared__ float wlds[CiCh * K * K * CoG];
  const int tid = threadIdx.x;
  const int gid = blockIdx.x * 256 + tid;
  const int t4 = gid & 63;
  const int w_ = (gid >> 6) % W;
  const int h_ = (gid / (64 * W)) % H;
  const int b  = gid / (64 * W * H);
  const int cob = blockIdx.y * CoG;

  float4 acc[CoG];
#pragma unroll
  for (int c = 0; c < CoG; ++c) acc[c] = make_float4(0.f, 0.f, 0.f, 0.f);

  for (int cic = 0; cic < Ci; cic += CiCh) {
    __syncthreads();
    // stage weights: lds[((cil*K+kh)*K+kw)*CoG + co]
    for (int idx = tid; idx < CiCh * K * K * CoG; idx += 256) {
      const int co  = idx % CoG;
      const int rr  = idx / CoG;
      const int cil = rr / (K * K);
      const int kk  = rr % (K * K);
      wlds[idx] = wt[(size_t)((cob + co) * Ci + cic + cil) * (K * K) + kk];
    }
    __syncthreads();
#pragma unroll 1
    for (int cil = 0; cil < CiCh; ++cil) {
      const float* inb = in + (size_t)((b * Ci + cic + cil) * H * W) * 256;
#pragma unroll 1
      for (int kh = 0; kh < K; ++kh) {
        const int hh = h_ + kh - P;
        if (hh < 0 || hh >= H) continue;      // wave-uniform (lanes share h,w)
#pragma unroll 1
        for (int kw = 0; kw < K; ++kw) {
          const int ww = w_ + kw - P;
          if (ww < 0 || ww >= W) continue;
          const float4 x = *(const float4*)(inb + (size_t)(hh * W + ww) * 256 + t4 * 4);
          const bool nz = (x.x != 0.f) | (x.y != 0.f) | (x.z != 0.f) | (x.w != 0.f);
          if (__any((int)nz)) {
            const float4* wr = (const float4*)&wlds[((cil * K + kh) * K + kw) * CoG];
#pragma unroll
            for (int c4 = 0; c4 < CoG / 4; ++c4) {
              const float4 wv = wr[c4];   // broadcast ds_read_b128
              acc[4*c4+0].x += x.x * wv.x; acc[4*c4+0].y += x.y * wv.x;
              acc[4*c4+0].z += x.z * wv.x; acc[4*c4+0].w += x.w * wv.x;
              acc[4*c4+1].x += x.x * wv.y; acc[4*c4+1].y += x.y * wv.y;
              acc[4*c4+1].z += x.z * wv.y; acc[4*c4+1].w += x.w * wv.y;
              acc[4*c4+2].x += x.x * wv.z; acc[4*c4+2].y += x.y * wv.z;
              acc[4*c4+2].z += x.z * wv.z; acc[4*c4+2].w += x.w * wv.z;
              acc[4*c4+3].x += x.x * wv.w; acc[4*c4+3].y += x.y * wv.w;
              acc[4*c4+3].z += x.z * wv.w; acc[4*c4+3].w += x.w * wv.w;
            }
          }
        }
      }
    }
  }
#pragma unroll
  for (int c = 0; c < CoG; ++c) {
    *(float4*)(out + (size_t)(((b * Co + cob + c) * H + h_) * W + w_) * 256 + t4 * 4) = acc[c];
  }
}

// ---------------------------------------------------------------------------
// Fused psp (2x IIR) + spike (refractory recursion), sequential over T.
// Thread = one (b,c,h,w) pixel; streams its contiguous 1KB row.
// ---------------------------------------------------------------------------
__global__ __launch_bounds__(256)
void psp_spike_kernel(const float* __restrict__ v, float* __restrict__ s, int npix) {
  const int pix = blockIdx.x * 256 + threadIdx.x;
  if (pix >= npix) return;
  const float4* vp = (const float4*)(v + (size_t)pix * 256);
  float4* sp = (float4*)(s + (size_t)pix * 256);
  float g1 = 0.f, g2 = 0.f, r = 0.f;
#pragma unroll 4
  for (int i = 0; i < 64; ++i) {
    const float4 x = vp[i];
    float4 o;
    o.x = snstep(x.x, g1, g2, r);
    o.y = snstep(x.y, g1, g2, r);
    o.z = snstep(x.z, g1, g2, r);
    o.w = snstep(x.w, g1, g2, r);
    sp[i] = o;
  }
}

// Fused 2x2 sumpool*2.75 + psp + spike. Thread = one pooled output pixel.
__global__ __launch_bounds__(256)
void pool_psp_spike_kernel(const float* __restrict__ in, float* __restrict__ out,
                           int PH, int PW, int npix) {
  const int pix = blockIdx.x * 256 + threadIdx.x;
  if (pix >= npix) return;
  const int pw = pix % PW;
  const int ph = (pix / PW) % PH;
  const int bc = pix / (PW * PH);
  const int W = 2 * PW, H = 2 * PH;
  const float* p00 = in + (size_t)((bc * H + 2 * ph) * W + 2 * pw) * 256;
  const float4* q00 = (const float4*)p00;
  const float4* q01 = (const float4*)(p00 + 256);
  const float4* q10 = (const float4*)(p00 + (size_t)W * 256);
  const float4* q11 = (const float4*)(p00 + (size_t)W * 256 + 256);
  float4* sp = (float4*)(out + (size_t)pix * 256);
  float g1 = 0.f, g2 = 0.f, r = 0.f;
#pragma unroll 4
  for (int i = 0; i < 64; ++i) {
    const float4 a = q00[i], bb = q01[i], c = q10[i], d = q11[i];
    float4 o;
    o.x = snstep((a.x + bb.x + c.x + d.x) * POOLSC, g1, g2, r);
    o.y = snstep((a.y + bb.y + c.y + d.y) * POOLSC, g1, g2, r);
    o.z = snstep((a.z + bb.z + c.z + d.z) * POOLSC, g1, g2, r);
    o.w = snstep((a.w + bb.w + c.w + d.w) * POOLSC, g1, g2, r);
    sp[i] = o;
  }
}

// Fused bilinear 2x upsample (half-pixel centers, clamped) + psp + spike.
// jax.image.resize 'bilinear' upsample: even i=2k -> 0.25*x[k-1]+0.75*x[k],
// odd i=2k+1 -> 0.75*x[k]+0.25*x[k+1], indices clamped (== boundary renorm).
__global__ __launch_bounds__(256)
void up_psp_spike_kernel(const float* __restrict__ in, float* __restrict__ out,
                         int IH, int IW, int npix) {
  const int pix = blockIdx.x * 256 + threadIdx.x;
  if (pix >= npix) return;
  const int OW = 2 * IW, OH = 2 * IH;
  const int ow = pix % OW;
  const int oh = (pix / OW) % OH;
  const int bc = pix / (OW * OH);
  int h0, h1, w0, w1; float fh0, fh1, fw0, fw1;
  {
    const int k = oh >> 1;
    if (oh & 1) { h0 = k; h1 = (k + 1 < IH) ? k + 1 : IH - 1; fh0 = 0.75f; fh1 = 0.25f; }
    else        { h0 = (k > 0) ? k - 1 : 0; h1 = k;           fh0 = 0.25f; fh1 = 0.75f; }
  }
  {
    const int k = ow >> 1;
    if (ow & 1) { w0 = k; w1 = (k + 1 < IW) ? k + 1 : IW - 1; fw0 = 0.75f; fw1 = 0.25f; }
    else        { w0 = (k > 0) ? k - 1 : 0; w1 = k;           fw0 = 0.25f; fw1 = 0.75f; }
  }
  const float c00 = fh0 * fw0, c01 = fh0 * fw1, c10 = fh1 * fw0, c11 = fh1 * fw1;
  const float4* q00 = (const float4*)(in + (size_t)((bc * IH + h0) * IW + w0) * 256);
  const float4* q01 = (const float4*)(in + (size_t)((bc * IH + h0) * IW + w1) * 256);
  const float4* q10 = (const float4*)(in + (size_t)((bc * IH + h1) * IW + w0) * 256);
  const float4* q11 = (const float4*)(in + (size_t)((bc * IH + h1) * IW + w1) * 256);
  float4* sp = (float4*)(out + (size_t)pix * 256);
  float g1 = 0.f, g2 = 0.f, r = 0.f;
#pragma unroll 4
  for (int i = 0; i < 64; ++i) {
    const float4 xa = q00[i], xb = q01[i], xc = q10[i], xd = q11[i];
    float4 o;
    o.x = snstep(c00 * xa.x + c01 * xb.x + c10 * xc.x + c11 * xd.x, g1, g2, r);
    o.y = snstep(c00 * xa.y + c01 * xb.y + c10 * xc.y + c11 * xd.y, g1, g2, r);
    o.z = snstep(c00 * xa.z + c01 * xb.z + c10 * xc.z + c11 * xd.z, g1, g2, r);
    o.w = snstep(c00 * xa.w + c01 * xb.w + c10 * xc.w + c11 * xd.w, g1, g2, r);
    sp[i] = o;
  }
}

// 1x1 conv (32 -> 1 channel). Thread = (b, h*32+w, t4).
__global__ __launch_bounds__(256)
void conv1x1_kernel(const float* __restrict__ in, const float* __restrict__ wt,
                    float* __restrict__ out) {
  const int gid = blockIdx.x * 256 + threadIdx.x;
  const int t4 = gid & 63;
  const int hw = (gid >> 6) & 1023;
  const int b  = gid >> 16;
  const float* base = in + (size_t)b * 32 * 32 * 32 * 256 + (size_t)hw * 256 + t4 * 4;
  float4 acc = make_float4(0.f, 0.f, 0.f, 0.f);
#pragma unroll 1
  for (int ci = 0; ci < 32; ++ci) {
    const float4 x = *(const float4*)(base + (size_t)ci * 32 * 32 * 256);
    const float wv = wt[ci];
    acc.x += x.x * wv; acc.y += x.y * wv; acc.z += x.z * wv; acc.w += x.w * wv;
  }
  *(float4*)(out + (size_t)(b * 1024 + hw) * 256 + t4 * 4) = acc;
}

// ---------------------------------------------------------------------------
// Orchestration. psp commutes with conv/pool/upsample (all linear, time-
// invariant), so each layer = op(spikes) [parallel] then psp+spike [temporal].
// Ping-pong two 64Mi-float buffers in d_ws (s_prev dead once op() consumed it).
// ---------------------------------------------------------------------------
extern "C" void kernel_launch(void* const* d_in, const int* in_sizes, int n_in,
                              void* d_out, int out_size, void* d_ws, size_t ws_size,
                              hipStream_t stream) {
  const float* x    = (const float*)d_in[0];  // [4,1,32,32,256]
  const float* w1   = (const float*)d_in[1];  // [16,1,5,5,1]
  const float* w2   = (const float*)d_in[2];  // [32,16,3,3,1]
  const float* w3   = (const float*)d_in[3];  // [64,32,3,3,1]
  const float* w4   = (const float*)d_in[4];  // [32,64,3,3,1]
  const float* wout = (const float*)d_in[5];  // [1,32,1,1,1]
  float* bufA = (float*)d_ws;
  float* bufB = bufA + (size_t)16 * 1024 * 1024;   // 64 Mi floats each
  float* out  = (float*)d_out;

  // L1: v1 = conv5x5(x) -> B ; s1 = spike(psp(v1)) -> A   [4,16,32,32,256]
  conv_kernel<1, 5, 2, 16, 16, 1, 32, 32><<<dim3(1024, 1), 256, 0, stream>>>(x, w1, bufB);
  psp_spike_kernel<<<256, 256, 0, stream>>>(bufB, bufA, 65536);
  // L2: s2 = spike(psp(pool(s1))) -> B                    [4,16,16,16,256]
  pool_psp_spike_kernel<<<64, 256, 0, stream>>>(bufA, bufB, 16, 16, 16384);
  // L3: v3 = conv3x3(s2) -> A ; s3 -> B                   [4,32,16,16,256]
  conv_kernel<16, 3, 1, 32, 32, 16, 16, 16><<<dim3(256, 1), 256, 0, stream>>>(bufB, w2, bufA);
  psp_spike_kernel<<<128, 256, 0, stream>>>(bufA, bufB, 32768);
  // L4: s4 -> A                                           [4,32,8,8,256]
  pool_psp_spike_kernel<<<32, 256, 0, stream>>>(bufB, bufA, 8, 8, 8192);
  // L5: v5 = conv3x3(s4) -> B ; s5 -> A                   [4,64,8,8,256]
  conv_kernel<32, 3, 1, 64, 32, 32, 8, 8><<<dim3(64, 2), 256, 0, stream>>>(bufA, w3, bufB);
  psp_spike_kernel<<<64, 256, 0, stream>>>(bufB, bufA, 16384);
  // L6: s6 = spike(psp(up2(s5))) -> B                     [4,64,16,16,256]
  up_psp_spike_kernel<<<256, 256, 0, stream>>>(bufA, bufB, 8, 8, 65536);
  // L7: v7 = conv3x3(s6) -> A ; s7 -> B                   [4,32,16,16,256]
  conv_kernel<64, 3, 1, 32, 32, 32, 16, 16><<<dim3(256, 1), 256, 0, stream>>>(bufB, w4, bufA);
  psp_spike_kernel<<<128, 256, 0, stream>>>(bufA, bufB, 32768);
  // L8: s8 -> A                                           [4,32,32,32,256]
  up_psp_spike_kernel<<<512, 256, 0, stream>>>(bufB, bufA, 16, 16, 131072);
  // L9: v9 = conv1x1(s8) -> B ; out = spike(psp(v9))      [4,1,32,32,256]
  conv1x1_kernel<<<1024, 256, 0, stream>>>(bufA, wout, bufB);
  psp_spike_kernel<<<16, 256, 0, stream>>>(bufB, out, 4096);
}

// Round 2
// 136.585 us; speedup vs baseline: 5.7555x; 5.7555x over previous
//
#include <hip/hip_runtime.h>

// SLAYER SRM-alpha constants (fp32-rounded from the reference doubles)
#define D_SR   0.90483741803595952f   // exp(-1/10)
#define D_REF  0.36787944117144233f   // exp(-1)
#define PSPSC  0.27182818284590454f   // e/10
#define THETA  10.0f
#define REFSC  20.0f                  // scaleRef * theta
#define POOLSC 2.75f                  // 1.1*theta/4

// One SRM step: two cascaded IIR stages (alpha PSP), threshold, exp refractory.
__device__ __forceinline__ float snstep(float x, float& g1, float& g2, float& r) {
  g1 = D_SR * g1 + x;
  g2 = D_SR * g2 + g1;
  const float u = PSPSC * (g2 - g1) + r - THETA;
  const float s = (u >= 0.0f) ? 1.0f : 0.0f;
  r = D_REF * (r - REFSC * s);
  return s;
}

// Zero the per-(b,channel) nonzero-flag arrays (ws is poisoned 0xAA each call).
__global__ __launch_bounds__(256)
void init_flags(unsigned* __restrict__ f, int n) {
  const int i = blockIdx.x * 256 + threadIdx.x;
  if (i < n) f[i] = 0u;
}

// ---------------------------------------------------------------------------
// L1 conv 5x5 (Ci=1, Co=16), dense float input. Thread=(b, pixel, t4-quad).
// b derived from blockIdx only (wave/block-uniform scalar flags downstream).
// Row-wise tap prefetch (5 outstanding loads) for latency hiding.
// ---------------------------------------------------------------------------
__global__ __launch_bounds__(256)
void conv1_kernel(const float* __restrict__ in, const float* __restrict__ wt,
                  float* __restrict__ out, unsigned* __restrict__ outflag) {
  const int H = 32, W = 32, K = 5, P = 2, Co = 16;
  __shared__ float wlds[25 * 16];
  const int tid = threadIdx.x;
  for (int idx = tid; idx < 25 * 16; idx += 256) {
    const int co = idx & 15, kk = idx >> 4;
    wlds[idx] = wt[co * 25 + kk];            // lds[kk*16+co]
  }
  __syncthreads();
  const int t4 = tid & 63;
  const int b = blockIdx.x >> 8;                        // 256 blocks / batch
  const int pixel = ((blockIdx.x & 255) << 2) + (tid >> 6);
  const int h_ = pixel >> 5, w_ = pixel & 31;
  float4 acc[16];
#pragma unroll
  for (int c = 0; c < 16; ++c) acc[c] = make_float4(0.f, 0.f, 0.f, 0.f);
  const float* inb = in + (size_t)b * H * W * 256;
#pragma unroll
  for (int kh = 0; kh < K; ++kh) {
    const int hh = h_ + kh - P;
    if (hh < 0 || hh >= H) continue;                    // block-uniform
    float4 xr[5];
#pragma unroll
    for (int kw = 0; kw < K; ++kw) {
      const int ww = w_ + kw - P;
      xr[kw] = (ww >= 0 && ww < W)
                 ? *(const float4*)(inb + (size_t)(hh * W + ww) * 256 + t4 * 4)
                 : make_float4(0.f, 0.f, 0.f, 0.f);
    }
#pragma unroll
    for (int kw = 0; kw < K; ++kw) {
      const float4 x = xr[kw];
      const bool nz = (x.x != 0.f) | (x.y != 0.f) | (x.z != 0.f) | (x.w != 0.f);
      if (__any((int)nz)) {
        const float4* wr = (const float4*)&wlds[(kh * K + kw) * 16];
#pragma unroll
        for (int c4 = 0; c4 < 4; ++c4) {
          const float4 wv = wr[c4];
          acc[4*c4+0].x += x.x * wv.x; acc[4*c4+0].y += x.y * wv.x;
          acc[4*c4+0].z += x.z * wv.x; acc[4*c4+0].w += x.w * wv.x;
          acc[4*c4+1].x += x.x * wv.y; acc[4*c4+1].y += x.y * wv.y;
          acc[4*c4+1].z += x.z * wv.y; acc[4*c4+1].w += x.w * wv.y;
          acc[4*c4+2].x += x.x * wv.z; acc[4*c4+2].y += x.y * wv.z;
          acc[4*c4+2].z += x.z * wv.z; acc[4*c4+2].w += x.w * wv.z;
          acc[4*c4+3].x += x.x * wv.w; acc[4*c4+3].y += x.y * wv.w;
          acc[4*c4+3].z += x.z * wv.w; acc[4*c4+3].w += x.w * wv.w;
        }
      }
    }
  }
#pragma unroll
  for (int c = 0; c < 16; ++c)
    *(float4*)(out + (size_t)(((b * Co + c) * H + h_) * W + w_) * 256 + t4 * 4) = acc[c];
  const bool lane0 = (t4 == 0);
#pragma unroll
  for (int c = 0; c < 16; ++c) {
    const float4 a = acc[c];
    const bool nz = (a.x != 0.f) | (a.y != 0.f) | (a.z != 0.f) | (a.w != 0.f);
    if (__any((int)nz) && lane0) outflag[b * Co + c] = 1u;
  }
}

// ---------------------------------------------------------------------------
// Gated 3x3 conv on uint8 spikes. Per-block 64-bit input-channel mask via
// ballot over flags; mask==0 -> immediate exit (consumer gated by outflag).
// All 9 taps of a channel prefetched (uchar4 = 1 VGPR each) before FMA.
// ---------------------------------------------------------------------------
template<int Ci, int K, int P, int Co, int CoG, int H, int W>
__global__ __launch_bounds__(256)
void conv_g_kernel(const unsigned char* __restrict__ in, const float* __restrict__ wt,
                   float* __restrict__ out, const unsigned* __restrict__ inflag,
                   unsigned* __restrict__ outflag) {
  const int bpb = H * W / 4;             // blocks per batch
  const int tid = threadIdx.x;
  const int b = blockIdx.x / bpb;        // block-uniform
  const int lane = tid & 63;
  const unsigned fv = (lane < Ci) ? inflag[b * Ci + lane] : 0u;
  const unsigned long long mask = __ballot(fv != 0u);
  if (mask == 0ull) return;              // whole block exits (uniform)

  __shared__ float wlds[Ci * K * K * CoG];
  const int cob = blockIdx.y * CoG;
  for (int idx = tid; idx < Ci * K * K * CoG; idx += 256) {
    const int co = idx % CoG;
    const int rr = idx / CoG;            // ci*K*K + kk
    wlds[idx] = wt[(size_t)(cob + co) * Ci * K * K + rr];
  }
  __syncthreads();

  const int pixel = (blockIdx.x % bpb) * 4 + (tid >> 6);
  const int h_ = pixel / W, w_ = pixel % W;
  float4 acc[CoG];
#pragma unroll
  for (int c = 0; c < CoG; ++c) acc[c] = make_float4(0.f, 0.f, 0.f, 0.f);

  for (int cil = 0; cil < Ci; ++cil) {
    if (!((mask >> cil) & 1ull)) continue;     // scalar skip of zero channels
    const unsigned char* inb = in + (size_t)((b * Ci + cil) * H * W) * 256;
    uchar4 u[K * K];
#pragma unroll
    for (int kh = 0; kh < K; ++kh)
#pragma unroll
      for (int kw = 0; kw < K; ++kw) {
        const int hh = h_ + kh - P, ww = w_ + kw - P;
        u[kh * K + kw] = (hh >= 0 && hh < H && ww >= 0 && ww < W)
            ? *(const uchar4*)(inb + (size_t)(hh * W + ww) * 256 + lane * 4)
            : make_uchar4(0, 0, 0, 0);
      }
#pragma unroll
    for (int tap = 0; tap < K * K; ++tap) {
      const uchar4 uu = u[tap];
      if (__any((int)(uu.x | uu.y | uu.z | uu.w))) {
        const float4 x = make_float4(uu.x, uu.y, uu.z, uu.w);
        const float4* wr = (const float4*)&wlds[(cil * K * K + tap) * CoG];
#pragma unroll
        for (int c4 = 0; c4 < CoG / 4; ++c4) {
          const float4 wv = wr[c4];
          acc[4*c4+0].x += x.x * wv.x; acc[4*c4+0].y += x.y * wv.x;
          acc[4*c4+0].z += x.z * wv.x; acc[4*c4+0].w += x.w * wv.x;
          acc[4*c4+1].x += x.x * wv.y; acc[4*c4+1].y += x.y * wv.y;
          acc[4*c4+1].z += x.z * wv.y; acc[4*c4+1].w += x.w * wv.y;
          acc[4*c4+2].x += x.x * wv.z; acc[4*c4+2].y += x.y * wv.z;
          acc[4*c4+2].z += x.z * wv.z; acc[4*c4+2].w += x.w * wv.z;
          acc[4*c4+3].x += x.x * wv.w; acc[4*c4+3].y += x.y * wv.w;
          acc[4*c4+3].z += x.z * wv.w; acc[4*c4+3].w += x.w * wv.w;
        }
      }
    }
  }
#pragma unroll
  for (int c = 0; c < CoG; ++c)
    *(float4*)(out + (size_t)(((b * Co + cob + c) * H + h_) * W + w_) * 256 + lane * 4) = acc[c];
  const bool lane0 = (lane == 0);
#pragma unroll
  for (int c = 0; c < CoG; ++c) {
    const float4 a = acc[c];
    const bool nz = (a.x != 0.f) | (a.y != 0.f) | (a.z != 0.f) | (a.w != 0.f);
    if (__any((int)nz) && lane0) outflag[b * Co + cob + c] = 1u;
  }
}

// ---------------------------------------------------------------------------
// Fused psp+spike: float membrane in -> uint8 spikes out, channel-gated.
// Thread = one pixel row (256 t contiguous). Skips zero channels entirely.
// ---------------------------------------------------------------------------
__global__ __launch_bounds__(256)
void psp_spike_u8(const float* __restrict__ v, unsigned char* __restrict__ s,
                  const unsigned* __restrict__ inflag, unsigned* __restrict__ outflag,
                  int HW, int npix) {
  const int pix = blockIdx.x * 256 + threadIdx.x;
  if (pix >= npix) return;
  const int bc = pix / HW;               // wave-uniform (HW multiple of 64)
  if (inflag[bc] == 0u) return;
  const float4* vp = (const float4*)(v + (size_t)pix * 256);
  uchar4* sp = (uchar4*)(s + (size_t)pix * 256);
  float g1 = 0.f, g2 = 0.f, r = 0.f;
  unsigned any = 0;
#pragma unroll 4
  for (int i = 0; i < 64; ++i) {
    const float4 x = vp[i];
    uchar4 o;
    o.x = (unsigned char)snstep(x.x, g1, g2, r);
    o.y = (unsigned char)snstep(x.y, g1, g2, r);
    o.z = (unsigned char)snstep(x.z, g1, g2, r);
    o.w = (unsigned char)snstep(x.w, g1, g2, r);
    any |= (unsigned)(o.x | o.y | o.z | o.w);
    sp[i] = o;
  }
  if (__any((int)any) && (threadIdx.x & 63) == 0) outflag[bc] = 1u;
}

// Fused 2x2 sumpool*2.75 + psp + spike on uint8 spikes, channel-gated.
__global__ __launch_bounds__(256)
void pool_u8(const unsigned char* __restrict__ in, unsigned char* __restrict__ out,
             const unsigned* __restrict__ inflag, unsigned* __restrict__ outflag,
             int PH, int PW, int npix) {
  const int pix = blockIdx.x * 256 + threadIdx.x;
  if (pix >= npix) return;
  const int pw = pix % PW, ph = (pix / PW) % PH, bc = pix / (PW * PH);
  if (inflag[bc] == 0u) return;
  const int W = 2 * PW, H = 2 * PH;
  const unsigned char* p00 = in + ((size_t)(bc * H + 2 * ph) * W + 2 * pw) * 256;
  const uchar4* q00 = (const uchar4*)p00;
  const uchar4* q01 = (const uchar4*)(p00 + 256);
  const uchar4* q10 = (const uchar4*)(p00 + (size_t)W * 256);
  const uchar4* q11 = (const uchar4*)(p00 + (size_t)W * 256 + 256);
  uchar4* sp = (uchar4*)(out + (size_t)pix * 256);
  float g1 = 0.f, g2 = 0.f, r = 0.f;
  unsigned any = 0;
#pragma unroll 4
  for (int i = 0; i < 64; ++i) {
    const uchar4 a = q00[i], b4 = q01[i], c = q10[i], d = q11[i];
    uchar4 o;
    o.x = (unsigned char)snstep((float)(a.x + b4.x + c.x + d.x) * POOLSC, g1, g2, r);
    o.y = (unsigned char)snstep((float)(a.y + b4.y + c.y + d.y) * POOLSC, g1, g2, r);
    o.z = (unsigned char)snstep((float)(a.z + b4.z + c.z + d.z) * POOLSC, g1, g2, r);
    o.w = (unsigned char)snstep((float)(a.w + b4.w + c.w + d.w) * POOLSC, g1, g2, r);
    any |= (unsigned)(o.x | o.y | o.z | o.w);
    sp[i] = o;
  }
  if (__any((int)any) && (threadIdx.x & 63) == 0) outflag[bc] = 1u;
}

// Fused bilinear 2x upsample + psp + spike on uint8 spikes, channel-gated.
// jax.image.resize bilinear 2x: even i=2k -> 0.25*x[k-1]+0.75*x[k] (clamped),
// odd i=2k+1 -> 0.75*x[k]+0.25*x[k+1] (clamped). Validated round 0 absmax=0.
__global__ __launch_bounds__(256)
void up_u8(const unsigned char* __restrict__ in, unsigned char* __restrict__ out,
           const unsigned* __restrict__ inflag, unsigned* __restrict__ outflag,
           int IH, int IW, int npix) {
  const int pix = blockIdx.x * 256 + threadIdx.x;
  if (pix >= npix) return;
  const int OW = 2 * IW, OH = 2 * IH;
  const int ow = pix % OW, oh = (pix / OW) % OH, bc = pix / (OW * OH);
  if (inflag[bc] == 0u) return;
  int h0, h1, w0, w1; float fh0, fh1, fw0, fw1;
  {
    const int k = oh >> 1;
    if (oh & 1) { h0 = k; h1 = (k + 1 < IH) ? k + 1 : IH - 1; fh0 = 0.75f; fh1 = 0.25f; }
    else        { h0 = (k > 0) ? k - 1 : 0; h1 = k;           fh0 = 0.25f; fh1 = 0.75f; }
  }
  {
    const int k = ow >> 1;
    if (ow & 1) { w0 = k; w1 = (k + 1 < IW) ? k + 1 : IW - 1; fw0 = 0.75f; fw1 = 0.25f; }
    else        { w0 = (k > 0) ? k - 1 : 0; w1 = k;           fw0 = 0.25f; fw1 = 0.75f; }
  }
  const float c00 = fh0 * fw0, c01 = fh0 * fw1, c10 = fh1 * fw0, c11 = fh1 * fw1;
  const uchar4* q00 = (const uchar4*)(in + ((size_t)(bc * IH + h0) * IW + w0) * 256);
  const uchar4* q01 = (const uchar4*)(in + ((size_t)(bc * IH + h0) * IW + w1) * 256);
  const uchar4* q10 = (const uchar4*)(in + ((size_t)(bc * IH + h1) * IW + w0) * 256);
  const uchar4* q11 = (const uchar4*)(in + ((size_t)(bc * IH + h1) * IW + w1) * 256);
  uchar4* sp = (uchar4*)(out + (size_t)pix * 256);
  float g1 = 0.f, g2 = 0.f, r = 0.f;
  unsigned any = 0;
#pragma unroll 4
  for (int i = 0; i < 64; ++i) {
    const uchar4 xa = q00[i], xb = q01[i], xc = q10[i], xd = q11[i];
    uchar4 o;
    o.x = (unsigned char)snstep(c00 * xa.x + c01 * xb.x + c10 * xc.x + c11 * xd.x, g1, g2, r);
    o.y = (unsigned char)snstep(c00 * xa.y + c01 * xb.y + c10 * xc.y + c11 * xd.y, g1, g2, r);
    o.z = (unsigned char)snstep(c00 * xa.z + c01 * xb.z + c10 * xc.z + c11 * xd.z, g1, g2, r);
    o.w = (unsigned char)snstep(c00 * xa.w + c01 * xb.w + c10 * xc.w + c11 * xd.w, g1, g2, r);
    any |= (unsigned)(o.x | o.y | o.z | o.w);
    sp[i] = o;
  }
  if (__any((int)any) && (threadIdx.x & 63) == 0) outflag[bc] = 1u;
}

// Gated 1x1 conv (32 -> 1) on uint8 spikes.
__global__ __launch_bounds__(256)
void conv1x1_g(const unsigned char* __restrict__ in, const float* __restrict__ wt,
               float* __restrict__ out, const unsigned* __restrict__ inflag,
               unsigned* __restrict__ outflag) {
  const int tid = threadIdx.x;
  const int b = blockIdx.x >> 8;          // 256 blocks / batch
  const int lane = tid & 63;
  const unsigned fv = (lane < 32) ? inflag[b * 32 + lane] : 0u;
  const unsigned long long mask = __ballot(fv != 0u);
  if (mask == 0ull) return;
  const int hw = ((blockIdx.x & 255) << 2) + (tid >> 6);
  float4 acc = make_float4(0.f, 0.f, 0.f, 0.f);
  for (int ci = 0; ci < 32; ++ci) {
    if (!((mask >> ci) & 1ull)) continue;
    const uchar4 u = *(const uchar4*)(in + ((size_t)((b * 32 + ci) * 1024 + hw)) * 256 + lane * 4);
    const float wv = wt[ci];
    acc.x += u.x * wv; acc.y += u.y * wv; acc.z += u.z * wv; acc.w += u.w * wv;
  }
  *(float4*)(out + ((size_t)(b * 1024 + hw)) * 256 + lane * 4) = acc;
  const bool nz = (acc.x != 0.f) | (acc.y != 0.f) | (acc.z != 0.f) | (acc.w != 0.f);
  if (__any((int)nz) && lane == 0) outflag[b] = 1u;
}

// Final psp+spike: ALWAYS writes d_out (zeros when channel flag is 0).
__global__ __launch_bounds__(256)
void out_psp(const float* __restrict__ v, float* __restrict__ o,
             const unsigned* __restrict__ f, int npix) {
  const int pix = blockIdx.x * 256 + threadIdx.x;
  if (pix >= npix) return;
  const int b = pix >> 10;                // HW=1024, C=1
  float4* op = (float4*)(o + (size_t)pix * 256);
  if (f[b] == 0u) {
    const float4 z = make_float4(0.f, 0.f, 0.f, 0.f);
#pragma unroll 4
    for (int i = 0; i < 64; ++i) op[i] = z;
    return;
  }
  const float4* vp = (const float4*)(v + (size_t)pix * 256);
  float g1 = 0.f, g2 = 0.f, r = 0.f;
#pragma unroll 4
  for (int i = 0; i < 64; ++i) {
    const float4 x = vp[i];
    float4 s;
    s.x = snstep(x.x, g1, g2, r);
    s.y = snstep(x.y, g1, g2, r);
    s.z = snstep(x.z, g1, g2, r);
    s.w = snstep(x.w, g1, g2, r);
    op[i] = s;
  }
}

// ---------------------------------------------------------------------------
// Orchestration. psp commutes with conv/pool/upsample (linear, time-invariant;
// validated R0 absmax=0): layer = op(spikes) then psp+spike. Spikes as uint8,
// per-(b,channel) nonzero flags gate all reads/writes of zero channels.
// Workspace (proven >= 128 MiB): V floats [0,68MiB), SA u8 [71,88), SB u8
// [92,126), flags [127MiB). No tensor aliasing (v_k dead after psp_k).
// ---------------------------------------------------------------------------
extern "C" void kernel_launch(void* const* d_in, const int* in_sizes, int n_in,
                              void* d_out, int out_size, void* d_ws, size_t ws_size,
                              hipStream_t stream) {
  const float* x    = (const float*)d_in[0];
  const float* w1   = (const float*)d_in[1];
  const float* w2   = (const float*)d_in[2];
  const float* w3   = (const float*)d_in[3];
  const float* w4   = (const float*)d_in[4];
  const float* wout = (const float*)d_in[5];
  char* ws = (char*)d_ws;
  float*         V  = (float*)ws;
  unsigned char* SA = (unsigned char*)(ws + (size_t)(71u << 20));
  unsigned char* SB = (unsigned char*)(ws + (size_t)(92u << 20));
  unsigned*      FL = (unsigned*)(ws + (size_t)(127u << 20));
  unsigned* fv1 = FL;         unsigned* fs1 = FL + 64;   unsigned* fs2 = FL + 128;
  unsigned* fv3 = FL + 192;   unsigned* fs3 = FL + 320;  unsigned* fs4 = FL + 448;
  unsigned* fv5 = FL + 576;   unsigned* fs5 = FL + 832;  unsigned* fs6 = FL + 1088;
  unsigned* fv7 = FL + 1344;  unsigned* fs7 = FL + 1472; unsigned* fs8 = FL + 1600;
  unsigned* fv9 = FL + 1728;  // 4
  float* out = (float*)d_out;

  init_flags<<<7, 256, 0, stream>>>(FL, 1732);
  // L1: v1 = conv5x5(x) [4,16,32,32,256] -> V ; s1 -> SA
  conv1_kernel<<<1024, 256, 0, stream>>>(x, w1, V, fv1);
  psp_spike_u8<<<256, 256, 0, stream>>>(V, SA, fv1, fs1, 1024, 65536);
  // L2: s2 = spike(psp(pool(s1))) [4,16,16,16,256] -> SB
  pool_u8<<<64, 256, 0, stream>>>(SA, SB, fs1, fs2, 16, 16, 16384);
  // L3: v3 = conv3x3(s2) [4,32,16,16,256] -> V ; s3 -> SA
  conv_g_kernel<16, 3, 1, 32, 16, 16, 16><<<dim3(256, 2), 256, 0, stream>>>(SB, w2, V, fs2, fv3);
  psp_spike_u8<<<128, 256, 0, stream>>>(V, SA, fv3, fs3, 256, 32768);
  // L4: s4 [4,32,8,8,256] -> SB
  pool_u8<<<32, 256, 0, stream>>>(SA, SB, fs3, fs4, 8, 8, 8192);
  // L5: v5 = conv3x3(s4) [4,64,8,8,256] -> V ; s5 -> SA
  conv_g_kernel<32, 3, 1, 64, 16, 8, 8><<<dim3(64, 4), 256, 0, stream>>>(SB, w3, V, fs4, fv5);
  psp_spike_u8<<<64, 256, 0, stream>>>(V, SA, fv5, fs5, 64, 16384);
  // L6: s6 = spike(psp(up2(s5))) [4,64,16,16,256] -> SB
  up_u8<<<256, 256, 0, stream>>>(SA, SB, fs5, fs6, 8, 8, 65536);
  // L7: v7 = conv3x3(s6) [4,32,16,16,256] -> V ; s7 -> SA
  conv_g_kernel<64, 3, 1, 32, 16, 16, 16><<<dim3(256, 2), 256, 0, stream>>>(SB, w4, V, fs6, fv7);
  psp_spike_u8<<<128, 256, 0, stream>>>(V, SA, fv7, fs7, 256, 32768);
  // L8: s8 [4,32,32,32,256] -> SB
  up_u8<<<512, 256, 0, stream>>>(SA, SB, fs7, fs8, 16, 16, 131072);
  // L9: v9 = conv1x1(s8) [4,1,32,32,256] -> V ; out = spike(psp(v9)) ALWAYS
  conv1x1_g<<<1024, 256, 0, stream>>>(SB, wout, V, fs8, fv9);
  out_psp<<<16, 256, 0, stream>>>(V, out, fv9, 4096);
}

// Round 3
// 123.692 us; speedup vs baseline: 6.3554x; 1.1042x over previous
//
#include <hip/hip_runtime.h>

// SLAYER SRM-alpha constants (fp32-rounded from the reference doubles)
#define D_SR   0.90483741803595952f   // exp(-1/10)
#define D_REF  0.36787944117144233f   // exp(-1)
#define PSPSC  0.27182818284590454f   // e/10
#define THETA  10.0f
#define REFSC  20.0f                  // scaleRef * theta
#define POOLSC 2.75f                  // 1.1*theta/4

typedef _Float16 half4_t __attribute__((ext_vector_type(4)));

// One SRM step: two cascaded IIR stages (alpha PSP), threshold, exp refractory.
__device__ __forceinline__ float snstep(float x, float& g1, float& g2, float& r) {
  g1 = D_SR * g1 + x;
  g2 = D_SR * g2 + g1;
  const float u = PSPSC * (g2 - g1) + r - THETA;
  const float s = (u >= 0.0f) ? 1.0f : 0.0f;
  r = D_REF * (r - REFSC * s);
  return s;
}

// Integer-spike variant for byte packing.
__device__ __forceinline__ int snstep_i(float x, float& g1, float& g2, float& r) {
  g1 = D_SR * g1 + x;
  g2 = D_SR * g2 + g1;
  const float u = PSPSC * (g2 - g1) + r - THETA;
  const int s = (u >= 0.0f) ? 1 : 0;
  r = D_REF * (r - REFSC * (float)s);
  return s;
}

// Zero the per-(b,channel) nonzero-flag arrays (ws is poisoned 0xAA each call).
__global__ __launch_bounds__(256)
void init_flags(unsigned* __restrict__ f, int n) {
  const int i = blockIdx.x * 256 + threadIdx.x;
  if (i < n) f[i] = 0u;
}

// ---------------------------------------------------------------------------
// Fused L1: conv5x5 (Ci=1,Co=16) + psp + spike, membrane never touches HBM.
// Phase 1: thread=(pl,t4) computes conv membrane (float4 over T), stores f16
//          into LDS rows [co*4+pl][t] (stride 260 halves = 520 B: 8B-aligned,
//          ~4-way-max bank pattern).
// Phase 2: wave 0, thread=row=(co,pl): sequential IIR+spike over 256 t from
//          LDS, packs spike bytes, dwordx4 stores to global, sets channel flag.
// LDS ~35 KB -> 4 blocks/CU -> 4 phase-2 waves/CU (all SIMDs busy).
// ---------------------------------------------------------------------------
__global__ __launch_bounds__(256, 4)
void fused_l1(const float* __restrict__ in, const float* __restrict__ wt,
              unsigned char* __restrict__ sout, unsigned* __restrict__ outflag) {
  const int H = 32, W = 32, K = 5, P = 2;
  __shared__ float wlds[25 * 16];
  __shared__ _Float16 vbuf[64 * 260];     // row r: stride 260 halves (520 B)
  const int tid = threadIdx.x;
  for (int idx = tid; idx < 25 * 16; idx += 256) {
    const int co = idx & 15, kk = idx >> 4;
    wlds[idx] = wt[co * 25 + kk];         // lds[kk*16+co]
  }
  __syncthreads();
  const int b = blockIdx.x >> 8;          // 256 blocks / batch
  const int pg = blockIdx.x & 255;        // 4-pixel group
  const int pl = tid >> 6, t4 = tid & 63;
  const int pixel = pg * 4 + pl;
  const int h_ = pixel >> 5, w_ = pixel & 31;

  float4 acc[16];
#pragma unroll
  for (int c = 0; c < 16; ++c) acc[c] = make_float4(0.f, 0.f, 0.f, 0.f);
  const float* inb = in + (size_t)b * H * W * 256;
#pragma unroll
  for (int kh = 0; kh < K; ++kh) {
    const int hh = h_ + kh - P;
    if (hh < 0 || hh >= H) continue;      // wave-uniform (lanes share pixel)
    float4 xr[5];
#pragma unroll
    for (int kw = 0; kw < K; ++kw) {
      const int ww = w_ + kw - P;
      xr[kw] = (ww >= 0 && ww < W)
                 ? *(const float4*)(inb + (size_t)(hh * W + ww) * 256 + t4 * 4)
                 : make_float4(0.f, 0.f, 0.f, 0.f);
    }
#pragma unroll
    for (int kw = 0; kw < K; ++kw) {
      const float4 x = xr[kw];            // input 10% dense: no __any skip
      const float4* wr = (const float4*)&wlds[(kh * K + kw) * 16];
#pragma unroll
      for (int c4 = 0; c4 < 4; ++c4) {
        const float4 wv = wr[c4];
        acc[4*c4+0].x += x.x * wv.x; acc[4*c4+0].y += x.y * wv.x;
        acc[4*c4+0].z += x.z * wv.x; acc[4*c4+0].w += x.w * wv.x;
        acc[4*c4+1].x += x.x * wv.y; acc[4*c4+1].y += x.y * wv.y;
        acc[4*c4+1].z += x.z * wv.y; acc[4*c4+1].w += x.w * wv.y;
        acc[4*c4+2].x += x.x * wv.z; acc[4*c4+2].y += x.y * wv.z;
        acc[4*c4+2].z += x.z * wv.z; acc[4*c4+2].w += x.w * wv.z;
        acc[4*c4+3].x += x.x * wv.w; acc[4*c4+3].y += x.y * wv.w;
        acc[4*c4+3].z += x.z * wv.w; acc[4*c4+3].w += x.w * wv.w;
      }
    }
  }
  // membrane -> LDS f16 (|v|<~1, psp gain ~27, threshold margin ~6: safe)
#pragma unroll
  for (int c = 0; c < 16; ++c) {
    half4_t hv;
    hv.x = (_Float16)acc[c].x; hv.y = (_Float16)acc[c].y;
    hv.z = (_Float16)acc[c].z; hv.w = (_Float16)acc[c].w;
    *(half4_t*)&vbuf[(c * 4 + pl) * 260 + t4 * 4] = hv;
  }
  __syncthreads();

  if (tid < 64) {                         // phase 2: one row per lane
    const int co = tid >> 2, pl2 = tid & 3;
    const int pix2 = pg * 4 + pl2;
    unsigned char* orow = sout + ((size_t)((b * 16 + co) * 1024 + pix2)) * 256;
    const _Float16* vrow = &vbuf[tid * 260];
    float g1 = 0.f, g2 = 0.f, r = 0.f;
    int any = 0;
#pragma unroll 2
    for (int i = 0; i < 16; ++i) {
      int4 pk;
      int* pw = &pk.x;
#pragma unroll
      for (int j = 0; j < 4; ++j) {
        const half4_t hv = *(const half4_t*)&vrow[i * 16 + j * 4];
        int d = 0;
        d |= snstep_i((float)hv.x, g1, g2, r);
        d |= snstep_i((float)hv.y, g1, g2, r) << 8;
        d |= snstep_i((float)hv.z, g1, g2, r) << 16;
        d |= snstep_i((float)hv.w, g1, g2, r) << 24;
        pw[j] = d;
      }
      any |= pk.x | pk.y | pk.z | pk.w;
      *(int4*)(orow + i * 16) = pk;
    }
    if (any) outflag[b * 16 + co] = 1u;
  }
}

// ---------------------------------------------------------------------------
// Gated 3x3 conv on uint8 spikes. Per-block 64-bit input-channel mask via
// ballot over flags; mask==0 -> immediate exit (consumer gated by outflag).
// ---------------------------------------------------------------------------
template<int Ci, int K, int P, int Co, int CoG, int H, int W>
__global__ __launch_bounds__(256)
void conv_g_kernel(const unsigned char* __restrict__ in, const float* __restrict__ wt,
                   float* __restrict__ out, const unsigned* __restrict__ inflag,
                   unsigned* __restrict__ outflag) {
  const int bpb = H * W / 4;             // blocks per batch
  const int tid = threadIdx.x;
  const int b = blockIdx.x / bpb;        // block-uniform
  const int lane = tid & 63;
  const unsigned fv = (lane < Ci) ? inflag[b * Ci + lane] : 0u;
  const unsigned long long mask = __ballot(fv != 0u);
  if (mask == 0ull) return;              // whole block exits (uniform)

  __shared__ float wlds[Ci * K * K * CoG];
  const int cob = blockIdx.y * CoG;
  for (int idx = tid; idx < Ci * K * K * CoG; idx += 256) {
    const int co = idx % CoG;
    const int rr = idx / CoG;            // ci*K*K + kk
    wlds[idx] = wt[(size_t)(cob + co) * Ci * K * K + rr];
  }
  __syncthreads();

  const int pixel = (blockIdx.x % bpb) * 4 + (tid >> 6);
  const int h_ = pixel / W, w_ = pixel % W;
  float4 acc[CoG];
#pragma unroll
  for (int c = 0; c < CoG; ++c) acc[c] = make_float4(0.f, 0.f, 0.f, 0.f);

  for (int cil = 0; cil < Ci; ++cil) {
    if (!((mask >> cil) & 1ull)) continue;     // scalar skip of zero channels
    const unsigned char* inb = in + (size_t)((b * Ci + cil) * H * W) * 256;
    uchar4 u[K * K];
#pragma unroll
    for (int kh = 0; kh < K; ++kh)
#pragma unroll
      for (int kw = 0; kw < K; ++kw) {
        const int hh = h_ + kh - P, ww = w_ + kw - P;
        u[kh * K + kw] = (hh >= 0 && hh < H && ww >= 0 && ww < W)
            ? *(const uchar4*)(inb + (size_t)(hh * W + ww) * 256 + lane * 4)
            : make_uchar4(0, 0, 0, 0);
      }
#pragma unroll
    for (int tap = 0; tap < K * K; ++tap) {
      const uchar4 uu = u[tap];
      if (__any((int)(uu.x | uu.y | uu.z | uu.w))) {
        const float4 x = make_float4(uu.x, uu.y, uu.z, uu.w);
        const float4* wr = (const float4*)&wlds[(cil * K * K + tap) * CoG];
#pragma unroll
        for (int c4 = 0; c4 < CoG / 4; ++c4) {
          const float4 wv = wr[c4];
          acc[4*c4+0].x += x.x * wv.x; acc[4*c4+0].y += x.y * wv.x;
          acc[4*c4+0].z += x.z * wv.x; acc[4*c4+0].w += x.w * wv.x;
          acc[4*c4+1].x += x.x * wv.y; acc[4*c4+1].y += x.y * wv.y;
          acc[4*c4+1].z += x.z * wv.y; acc[4*c4+1].w += x.w * wv.y;
          acc[4*c4+2].x += x.x * wv.z; acc[4*c4+2].y += x.y * wv.z;
          acc[4*c4+2].z += x.z * wv.z; acc[4*c4+2].w += x.w * wv.z;
          acc[4*c4+3].x += x.x * wv.w; acc[4*c4+3].y += x.y * wv.w;
          acc[4*c4+3].z += x.z * wv.w; acc[4*c4+3].w += x.w * wv.w;
        }
      }
    }
  }
#pragma unroll
  for (int c = 0; c < CoG; ++c)
    *(float4*)(out + (size_t)(((b * Co + cob + c) * H + h_) * W + w_) * 256 + lane * 4) = acc[c];
  const bool lane0 = (lane == 0);
#pragma unroll
  for (int c = 0; c < CoG; ++c) {
    const float4 a = acc[c];
    const bool nz = (a.x != 0.f) | (a.y != 0.f) | (a.z != 0.f) | (a.w != 0.f);
    if (__any((int)nz) && lane0) outflag[b * Co + cob + c] = 1u;
  }
}

// ---------------------------------------------------------------------------
// Fused psp+spike: float membrane in -> uint8 spikes out, channel-gated.
// ---------------------------------------------------------------------------
__global__ __launch_bounds__(256)
void psp_spike_u8(const float* __restrict__ v, unsigned char* __restrict__ s,
                  const unsigned* __restrict__ inflag, unsigned* __restrict__ outflag,
                  int HW, int npix) {
  const int pix = blockIdx.x * 256 + threadIdx.x;
  if (pix >= npix) return;
  const int bc = pix / HW;               // wave-uniform (HW multiple of 64)
  if (inflag[bc] == 0u) return;
  const float4* vp = (const float4*)(v + (size_t)pix * 256);
  uchar4* sp = (uchar4*)(s + (size_t)pix * 256);
  float g1 = 0.f, g2 = 0.f, r = 0.f;
  unsigned any = 0;
#pragma unroll 4
  for (int i = 0; i < 64; ++i) {
    const float4 x = vp[i];
    uchar4 o;
    o.x = (unsigned char)snstep(x.x, g1, g2, r);
    o.y = (unsigned char)snstep(x.y, g1, g2, r);
    o.z = (unsigned char)snstep(x.z, g1, g2, r);
    o.w = (unsigned char)snstep(x.w, g1, g2, r);
    any |= (unsigned)(o.x | o.y | o.z | o.w);
    sp[i] = o;
  }
  if (__any((int)any) && (threadIdx.x & 63) == 0) outflag[bc] = 1u;
}

// Fused 2x2 sumpool*2.75 + psp + spike on uint8 spikes, channel-gated.
__global__ __launch_bounds__(256)
void pool_u8(const unsigned char* __restrict__ in, unsigned char* __restrict__ out,
             const unsigned* __restrict__ inflag, unsigned* __restrict__ outflag,
             int PH, int PW, int npix) {
  const int pix = blockIdx.x * 256 + threadIdx.x;
  if (pix >= npix) return;
  const int pw = pix % PW, ph = (pix / PW) % PH, bc = pix / (PW * PH);
  if (inflag[bc] == 0u) return;
  const int W = 2 * PW, H = 2 * PH;
  const unsigned char* p00 = in + ((size_t)(bc * H + 2 * ph) * W + 2 * pw) * 256;
  const uchar4* q00 = (const uchar4*)p00;
  const uchar4* q01 = (const uchar4*)(p00 + 256);
  const uchar4* q10 = (const uchar4*)(p00 + (size_t)W * 256);
  const uchar4* q11 = (const uchar4*)(p00 + (size_t)W * 256 + 256);
  uchar4* sp = (uchar4*)(out + (size_t)pix * 256);
  float g1 = 0.f, g2 = 0.f, r = 0.f;
  unsigned any = 0;
#pragma unroll 4
  for (int i = 0; i < 64; ++i) {
    const uchar4 a = q00[i], b4 = q01[i], c = q10[i], d = q11[i];
    uchar4 o;
    o.x = (unsigned char)snstep((float)(a.x + b4.x + c.x + d.x) * POOLSC, g1, g2, r);
    o.y = (unsigned char)snstep((float)(a.y + b4.y + c.y + d.y) * POOLSC, g1, g2, r);
    o.z = (unsigned char)snstep((float)(a.z + b4.z + c.z + d.z) * POOLSC, g1, g2, r);
    o.w = (unsigned char)snstep((float)(a.w + b4.w + c.w + d.w) * POOLSC, g1, g2, r);
    any |= (unsigned)(o.x | o.y | o.z | o.w);
    sp[i] = o;
  }
  if (__any((int)any) && (threadIdx.x & 63) == 0) outflag[bc] = 1u;
}

// Fused bilinear 2x upsample + psp + spike on uint8 spikes, channel-gated.
// jax.image.resize bilinear 2x: even i=2k -> 0.25*x[k-1]+0.75*x[k] (clamped),
// odd i=2k+1 -> 0.75*x[k]+0.25*x[k+1] (clamped). Validated R0/R1 absmax=0.
__global__ __launch_bounds__(256)
void up_u8(const unsigned char* __restrict__ in, unsigned char* __restrict__ out,
           const unsigned* __restrict__ inflag, unsigned* __restrict__ outflag,
           int IH, int IW, int npix) {
  const int pix = blockIdx.x * 256 + threadIdx.x;
  if (pix >= npix) return;
  const int OW = 2 * IW, OH = 2 * IH;
  const int ow = pix % OW, oh = (pix / OW) % OH, bc = pix / (OW * OH);
  if (inflag[bc] == 0u) return;
  int h0, h1, w0, w1; float fh0, fh1, fw0, fw1;
  {
    const int k = oh >> 1;
    if (oh & 1) { h0 = k; h1 = (k + 1 < IH) ? k + 1 : IH - 1; fh0 = 0.75f; fh1 = 0.25f; }
    else        { h0 = (k > 0) ? k - 1 : 0; h1 = k;           fh0 = 0.25f; fh1 = 0.75f; }
  }
  {
    const int k = ow >> 1;
    if (ow & 1) { w0 = k; w1 = (k + 1 < IW) ? k + 1 : IW - 1; fw0 = 0.75f; fw1 = 0.25f; }
    else        { w0 = (k > 0) ? k - 1 : 0; w1 = k;           fw0 = 0.25f; fw1 = 0.75f; }
  }
  const float c00 = fh0 * fw0, c01 = fh0 * fw1, c10 = fh1 * fw0, c11 = fh1 * fw1;
  const uchar4* q00 = (const uchar4*)(in + ((size_t)(bc * IH + h0) * IW + w0) * 256);
  const uchar4* q01 = (const uchar4*)(in + ((size_t)(bc * IH + h0) * IW + w1) * 256);
  const uchar4* q10 = (const uchar4*)(in + ((size_t)(bc * IH + h1) * IW + w0) * 256);
  const uchar4* q11 = (const uchar4*)(in + ((size_t)(bc * IH + h1) * IW + w1) * 256);
  uchar4* sp = (uchar4*)(out + (size_t)pix * 256);
  float g1 = 0.f, g2 = 0.f, r = 0.f;
  unsigned any = 0;
#pragma unroll 4
  for (int i = 0; i < 64; ++i) {
    const uchar4 xa = q00[i], xb = q01[i], xc = q10[i], xd = q11[i];
    uchar4 o;
    o.x = (unsigned char)snstep(c00 * xa.x + c01 * xb.x + c10 * xc.x + c11 * xd.x, g1, g2, r);
    o.y = (unsigned char)snstep(c00 * xa.y + c01 * xb.y + c10 * xc.y + c11 * xd.y, g1, g2, r);
    o.z = (unsigned char)snstep(c00 * xa.z + c01 * xb.z + c10 * xc.z + c11 * xd.z, g1, g2, r);
    o.w = (unsigned char)snstep(c00 * xa.w + c01 * xb.w + c10 * xc.w + c11 * xd.w, g1, g2, r);
    any |= (unsigned)(o.x | o.y | o.z | o.w);
    sp[i] = o;
  }
  if (__any((int)any) && (threadIdx.x & 63) == 0) outflag[bc] = 1u;
}

// Gated 1x1 conv (32 -> 1) on uint8 spikes.
__global__ __launch_bounds__(256)
void conv1x1_g(const unsigned char* __restrict__ in, const float* __restrict__ wt,
               float* __restrict__ out, const unsigned* __restrict__ inflag,
               unsigned* __restrict__ outflag) {
  const int tid = threadIdx.x;
  const int b = blockIdx.x >> 8;          // 256 blocks / batch
  const int lane = tid & 63;
  const unsigned fv = (lane < 32) ? inflag[b * 32 + lane] : 0u;
  const unsigned long long mask = __ballot(fv != 0u);
  if (mask == 0ull) return;
  const int hw = ((blockIdx.x & 255) << 2) + (tid >> 6);
  float4 acc = make_float4(0.f, 0.f, 0.f, 0.f);
  for (int ci = 0; ci < 32; ++ci) {
    if (!((mask >> ci) & 1ull)) continue;
    const uchar4 u = *(const uchar4*)(in + ((size_t)((b * 32 + ci) * 1024 + hw)) * 256 + lane * 4);
    const float wv = wt[ci];
    acc.x += u.x * wv; acc.y += u.y * wv; acc.z += u.z * wv; acc.w += u.w * wv;
  }
  *(float4*)(out + ((size_t)(b * 1024 + hw)) * 256 + lane * 4) = acc;
  const bool nz = (acc.x != 0.f) | (acc.y != 0.f) | (acc.z != 0.f) | (acc.w != 0.f);
  if (__any((int)nz) && lane == 0) outflag[b] = 1u;
}

// Final psp+spike: ALWAYS writes d_out (zeros when channel flag is 0).
__global__ __launch_bounds__(256)
void out_psp(const float* __restrict__ v, float* __restrict__ o,
             const unsigned* __restrict__ f, int npix) {
  const int pix = blockIdx.x * 256 + threadIdx.x;
  if (pix >= npix) return;
  const int b = pix >> 10;                // HW=1024, C=1
  float4* op = (float4*)(o + (size_t)pix * 256);
  if (f[b] == 0u) {
    const float4 z = make_float4(0.f, 0.f, 0.f, 0.f);
#pragma unroll 4
    for (int i = 0; i < 64; ++i) op[i] = z;
    return;
  }
  const float4* vp = (const float4*)(v + (size_t)pix * 256);
  float g1 = 0.f, g2 = 0.f, r = 0.f;
#pragma unroll 4
  for (int i = 0; i < 64; ++i) {
    const float4 x = vp[i];
    float4 s;
    s.x = snstep(x.x, g1, g2, r);
    s.y = snstep(x.y, g1, g2, r);
    s.z = snstep(x.z, g1, g2, r);
    s.w = snstep(x.w, g1, g2, r);
    op[i] = s;
  }
}

// ---------------------------------------------------------------------------
// Orchestration. psp commutes with conv/pool/upsample (linear, time-invariant;
// validated absmax=0 R0-R2). L1 fully fused (conv+psp+spike via LDS membrane);
// downstream layers remain flag-gated (exit in ~µs when spikes are absent,
// fully correct when present). Spikes stored as uint8.
// Workspace: V floats [0,68MiB), SA u8 [71,88), SB u8 [92,126), flags [127MiB).
// ---------------------------------------------------------------------------
extern "C" void kernel_launch(void* const* d_in, const int* in_sizes, int n_in,
                              void* d_out, int out_size, void* d_ws, size_t ws_size,
                              hipStream_t stream) {
  const float* x    = (const float*)d_in[0];
  const float* w1   = (const float*)d_in[1];
  const float* w2   = (const float*)d_in[2];
  const float* w3   = (const float*)d_in[3];
  const float* w4   = (const float*)d_in[4];
  const float* wout = (const float*)d_in[5];
  char* ws = (char*)d_ws;
  float*         V  = (float*)ws;
  unsigned char* SA = (unsigned char*)(ws + (size_t)(71u << 20));
  unsigned char* SB = (unsigned char*)(ws + (size_t)(92u << 20));
  unsigned*      FL = (unsigned*)(ws + (size_t)(127u << 20));
  unsigned* fs1 = FL + 64;   unsigned* fs2 = FL + 128;
  unsigned* fv3 = FL + 192;  unsigned* fs3 = FL + 320;  unsigned* fs4 = FL + 448;
  unsigned* fv5 = FL + 576;  unsigned* fs5 = FL + 832;  unsigned* fs6 = FL + 1088;
  unsigned* fv7 = FL + 1344; unsigned* fs7 = FL + 1472; unsigned* fs8 = FL + 1600;
  unsigned* fv9 = FL + 1728;
  float* out = (float*)d_out;

  init_flags<<<7, 256, 0, stream>>>(FL, 1732);
  // L1 fused: s1 = spike(psp(conv5x5(x))) [4,16,32,32,256] -> SA
  fused_l1<<<1024, 256, 0, stream>>>(x, w1, SA, fs1);
  // L2: s2 = spike(psp(pool(s1))) [4,16,16,16,256] -> SB
  pool_u8<<<64, 256, 0, stream>>>(SA, SB, fs1, fs2, 16, 16, 16384);
  // L3: v3 = conv3x3(s2) [4,32,16,16,256] -> V ; s3 -> SA
  conv_g_kernel<16, 3, 1, 32, 16, 16, 16><<<dim3(256, 2), 256, 0, stream>>>(SB, w2, V, fs2, fv3);
  psp_spike_u8<<<128, 256, 0, stream>>>(V, SA, fv3, fs3, 256, 32768);
  // L4: s4 [4,32,8,8,256] -> SB
  pool_u8<<<32, 256, 0, stream>>>(SA, SB, fs3, fs4, 8, 8, 8192);
  // L5: v5 = conv3x3(s4) [4,64,8,8,256] -> V ; s5 -> SA
  conv_g_kernel<32, 3, 1, 64, 16, 8, 8><<<dim3(64, 4), 256, 0, stream>>>(SB, w3, V, fs4, fv5);
  psp_spike_u8<<<64, 256, 0, stream>>>(V, SA, fv5, fs5, 64, 16384);
  // L6: s6 = spike(psp(up2(s5))) [4,64,16,16,256] -> SB
  up_u8<<<256, 256, 0, stream>>>(SA, SB, fs5, fs6, 8, 8, 65536);
  // L7: v7 = conv3x3(s6) [4,32,16,16,256] -> V ; s7 -> SA
  conv_g_kernel<64, 3, 1, 32, 16, 16, 16><<<dim3(256, 2), 256, 0, stream>>>(SB, w4, V, fs6, fv7);
  psp_spike_u8<<<128, 256, 0, stream>>>(V, SA, fv7, fs7, 256, 32768);
  // L8: s8 [4,32,32,32,256] -> SB
  up_u8<<<512, 256, 0, stream>>>(SA, SB, fs7, fs8, 16, 16, 131072);
  // L9: v9 = conv1x1(s8) [4,1,32,32,256] -> V ; out = spike(psp(v9)) ALWAYS
  conv1x1_g<<<1024, 256, 0, stream>>>(SB, wout, V, fs8, fv9);
  out_psp<<<16, 256, 0, stream>>>(V, out, fv9, 4096);
}